// Round 1
// baseline (617.619 us; speedup 1.0000x reference)
//
#include <hip/hip_runtime.h>
#include <hip/hip_bf16.h>
#include <stdint.h>

#define L_ 128
#define B_ 4
#define H_ 768
#define R_ 97
#define RP_ 128          // padded R for phase-2 tiling
#define LN_EPS 1e-5f

// ---------------- prep: concat [h_re1 | h_re2] -> cc[512][1536] ----------------
__global__ __launch_bounds__(256) void concat_kernel(const float* __restrict__ h1,
                                                     const float* __restrict__ h2,
                                                     float* __restrict__ cc) {
  int lb = blockIdx.x;                       // 0..511  (l*B+b)
  const float* s1 = h1 + (size_t)lb * H_;
  const float* s2 = h2 + (size_t)lb * H_;
  float* d = cc + (size_t)lb * (2 * H_);
  for (int i = threadIdx.x; i < H_; i += 256) d[i] = s1[i];
  for (int i = threadIdx.x; i < H_; i += 256) d[H_ + i] = s2[i];
}

// ---------------- prep: tiled transpose with optional zero-pad ----------------
// BT[k][n] (ld = NP) = n < N ? B[n*ldb + off + k] : 0
__global__ __launch_bounds__(256) void transpose_pad(const float* __restrict__ B,
                                                     float* __restrict__ BT,
                                                     int N, int K, int ldb, int off, int NP) {
  __shared__ float t[32][33];
  int kb = blockIdx.x * 32, nb = blockIdx.y * 32;
  int tx = threadIdx.x & 31, ty = threadIdx.x >> 5;   // ty 0..7
#pragma unroll
  for (int j = 0; j < 4; ++j) {
    int n = nb + ty + 8 * j;
    t[ty + 8 * j][tx] = (n < N) ? B[(size_t)n * ldb + off + kb + tx] : 0.f;
  }
  __syncthreads();
#pragma unroll
  for (int j = 0; j < 4; ++j) {
    BT[(size_t)(kb + ty + 8 * j) * NP + nb + tx] = t[tx][ty + 8 * j];
  }
}

// ---------------- small NT GEMM: C[m][n] = act(sum_k A[m][k]*BT[k][n] + bias[n]) ----------
// BT is [K][N] row-major (ld = N). Tile 16(m) x 128(n), 256 threads, micro 2x4.
template <int ACT>   // 0 = none, 1 = tanh
__global__ __launch_bounds__(256) void gemm_bt(const float* __restrict__ A, int lda,
                                               const float* __restrict__ BT,
                                               const float* __restrict__ bias,
                                               float* __restrict__ C,
                                               int M, int N, int K) {
  int tid = threadIdx.x;
  int n0 = blockIdx.x * 128 + (tid & 31) * 4;
  int m0 = blockIdx.y * 16 + (tid >> 5) * 2;
  int r0 = m0 < M ? m0 : 0;          // clamp (rows beyond M never written)
  int r1 = (m0 + 1) < M ? (m0 + 1) : 0;
  const float* a0 = A + (size_t)r0 * lda;
  const float* a1 = A + (size_t)r1 * lda;
  const float* bp = BT + n0;
  float acc0[4] = {0.f, 0.f, 0.f, 0.f};
  float acc1[4] = {0.f, 0.f, 0.f, 0.f};
#pragma unroll 4
  for (int k = 0; k < K; ++k) {
    float4 b4 = *(const float4*)bp;
    bp += N;
    float x0 = a0[k], x1 = a1[k];
    acc0[0] += x0 * b4.x; acc0[1] += x0 * b4.y; acc0[2] += x0 * b4.z; acc0[3] += x0 * b4.w;
    acc1[0] += x1 * b4.x; acc1[1] += x1 * b4.y; acc1[2] += x1 * b4.z; acc1[3] += x1 * b4.w;
  }
  float bi[4];
#pragma unroll
  for (int c = 0; c < 4; ++c) bi[c] = bias ? bias[n0 + c] : 0.f;
  if (m0 < M) {
#pragma unroll
    for (int c = 0; c < 4; ++c) {
      float v = acc0[c] + bi[c];
      if (ACT == 1) v = tanhf(v);
      C[(size_t)m0 * N + n0 + c] = v;
    }
  }
  if (m0 + 1 < M) {
#pragma unroll
    for (int c = 0; c < 4; ++c) {
      float v = acc1[c] + bi[c];
      if (ACT == 1) v = tanhf(v);
      C[(size_t)(m0 + 1) * N + n0 + c] = v;
    }
  }
}

// ---------------- max over l: gmax[b][h] = max_l g[(l*B+b)][h] ----------------
__global__ __launch_bounds__(256) void maxred_kernel(const float* __restrict__ g,
                                                     float* __restrict__ gmax) {
  int t = blockIdx.x * 256 + threadIdx.x;   // 0..3071
  if (t >= B_ * H_) return;
  int b = t / H_, h = t - b * H_;
  float m = -3.4e38f;
  for (int l = 0; l < L_; ++l) m = fmaxf(m, g[((size_t)(l * B_ + b)) * H_ + h]);
  gmax[t] = m;
}

// ---------------- fused: pre -> LN -> ELU -> proj(Wo) -> sigmoid*mask ----------------
// block = 32 rows of the 65536-row (k,l,b) space; 256 threads = 4 waves.
__global__ __launch_bounds__(256) void fused_kernel(const float* __restrict__ a,
                                                    const float* __restrict__ b2,
                                                    const float* __restrict__ gp,
                                                    const float* __restrict__ gamma,
                                                    const float* __restrict__ beta,
                                                    const float* __restrict__ WoT,  // [768][128]
                                                    const float* __restrict__ bo,
                                                    const float* __restrict__ mask, // [L][B]
                                                    float* __restrict__ out) {
  __shared__ __hip_bfloat16 Xs[32 * H_];      // 48 KB
  int m0 = blockIdx.x * 32;
  int tid = threadIdx.x;
  int lane = tid & 63, w = tid >> 6;
  int kk = m0 >> 9;                           // row / (L_*... ) -> k index (fixed per block)

  // ---- phase 1: LN+ELU rows -> bf16 in LDS (wave w owns rows 8w..8w+7) ----
  for (int j = 0; j < 8; ++j) {
    int rr = w * 8 + j;
    int row = m0 + rr;
    int b = row & 3, l = (row >> 2) & 127;
    const float* ar = a + (size_t)(kk * B_ + b) * H_;
    const float* brow = b2 + (size_t)(l * B_ + b) * H_;
    const float* gr = gp + (size_t)b * H_;
    float v[12];
    float s = 0.f, sq = 0.f;
#pragma unroll
    for (int t = 0; t < 12; ++t) {
      int h = lane + 64 * t;
      float x = ar[h] + brow[h] + gr[h];
      v[t] = x;
      s += x;
      sq += x * x;
    }
#pragma unroll
    for (int off = 32; off; off >>= 1) {
      s += __shfl_xor(s, off);
      sq += __shfl_xor(sq, off);
    }
    float mu = s * (1.f / H_);
    float var = sq * (1.f / H_) - mu * mu;
    float rs = rsqrtf(var + LN_EPS);
#pragma unroll
    for (int t = 0; t < 12; ++t) {
      int h = lane + 64 * t;
      float y = (v[t] - mu) * rs * gamma[h] + beta[h];
      float x = y > 0.f ? y : (__expf(y) - 1.f);   // elu, alpha=1
      Xs[rr * H_ + h] = __float2bfloat16(x);
    }
  }
  __syncthreads();

  // ---- phase 2: C[32][97] = X[32][768] * WoT ; micro 4 rows x 4 cols ----
  int tc = tid & 31, tm = tid >> 5;
  int c0 = tc * 4;
  float acc[4][4] = {};
  for (int k0 = 0; k0 < H_; k0 += 4) {
    float xv[4][4];
#pragma unroll
    for (int i = 0; i < 4; ++i) {
      uint2 p = *(const uint2*)((const uint16_t*)Xs + (size_t)(tm * 4 + i) * H_ + k0);
      xv[i][0] = __uint_as_float(p.x << 16);
      xv[i][1] = __uint_as_float(p.x & 0xffff0000u);
      xv[i][2] = __uint_as_float(p.y << 16);
      xv[i][3] = __uint_as_float(p.y & 0xffff0000u);
    }
#pragma unroll
    for (int kq = 0; kq < 4; ++kq) {
      float4 wv = *(const float4*)(WoT + (size_t)(k0 + kq) * RP_ + c0);
#pragma unroll
      for (int i = 0; i < 4; ++i) {
        acc[i][0] += xv[i][kq] * wv.x;
        acc[i][1] += xv[i][kq] * wv.y;
        acc[i][2] += xv[i][kq] * wv.z;
        acc[i][3] += xv[i][kq] * wv.w;
      }
    }
  }
  // ---- epilogue: bias, sigmoid, mask, store ----
  if (c0 < R_) {
#pragma unroll
    for (int i = 0; i < 4; ++i) {
      int row = m0 + tm * 4 + i;
      int b = row & 3, l = (row >> 2) & 127;
      float mv = mask[kk * B_ + b] * mask[l * B_ + b];
      float* op = out + (size_t)row * R_;
#pragma unroll
      for (int c = 0; c < 4; ++c) {
        if (c0 + c < R_) {
          float z = acc[i][c] + bo[c0 + c];
          op[c0 + c] = mv / (1.f + __expf(-z));
        }
      }
    }
  }
}

extern "C" void kernel_launch(void* const* d_in, const int* in_sizes, int n_in,
                              void* d_out, int out_size, void* d_ws, size_t ws_size,
                              hipStream_t stream) {
  const float* h1    = (const float*)d_in[0];
  const float* h2    = (const float*)d_in[1];
  const float* mask  = (const float*)d_in[2];
  const float* Wr    = (const float*)d_in[3];
  const float* br    = (const float*)d_in[4];
  const float* Wh    = (const float*)d_in[5];
  const float* bh    = (const float*)d_in[6];
  const float* gamma = (const float*)d_in[7];
  const float* beta  = (const float*)d_in[8];
  const float* Wo    = (const float*)d_in[9];
  const float* bo    = (const float*)d_in[10];
  float* out = (float*)d_out;
  float* ws = (float*)d_ws;

  // ws layout (floats). aM/b2M alias WrT (dead after gemm1).
  float* WrT  = ws;                      // 1536*768 = 1,179,648
  float* cc   = WrT + 1179648;           //  512*1536 =   786,432
  float* W1T  = cc + 786432;             //  768*768 =    589,824
  float* W2T  = W1T + 589824;
  float* W3T  = W2T + 589824;
  float* WoT  = W3T + 589824;            //  768*128 =     98,304
  float* g    = WoT + 98304;             //  512*768 =    393,216
  float* gmax = g + 393216;              //  3072
  float* gpb  = gmax + 3072;             //  3072
  float* aM   = WrT;                     //  alias: 393,216
  float* b2M  = WrT + 393216;            //  alias: 393,216

  concat_kernel<<<512, 256, 0, stream>>>(h1, h2, cc);
  transpose_pad<<<dim3(1536 / 32, 768 / 32), 256, 0, stream>>>(Wr, WrT, 768, 1536, 1536, 0, 768);
  transpose_pad<<<dim3(768 / 32, 768 / 32), 256, 0, stream>>>(Wh, W1T, 768, 768, 2304, 0, 768);
  transpose_pad<<<dim3(768 / 32, 768 / 32), 256, 0, stream>>>(Wh, W2T, 768, 768, 2304, 768, 768);
  transpose_pad<<<dim3(768 / 32, 768 / 32), 256, 0, stream>>>(Wh, W3T, 768, 768, 2304, 1536, 768);
  transpose_pad<<<dim3(768 / 32, 128 / 32), 256, 0, stream>>>(Wo, WoT, 97, 768, 768, 0, RP_);

  // g = tanh(cc @ WrT + br)   [512][768]
  gemm_bt<1><<<dim3(6, 32), 256, 0, stream>>>(cc, 2 * H_, WrT, br, g, 512, 768, 1536);
  // gmax[b][h] = max_l g
  maxred_kernel<<<12, 256, 0, stream>>>(g, gmax);
  // a = h2 @ W1T, b2 = h2 @ W2T   [512][768]   (note: aM/b2M overwrite WrT region — gemm1 already done)
  gemm_bt<0><<<dim3(6, 32), 256, 0, stream>>>(h2, H_, W1T, nullptr, aM, 512, 768, 768);
  gemm_bt<0><<<dim3(6, 32), 256, 0, stream>>>(h2, H_, W2T, nullptr, b2M, 512, 768, 768);
  // gp = gmax @ W3T + bh   [4][768]
  gemm_bt<0><<<dim3(6, 1), 256, 0, stream>>>(gmax, H_, W3T, bh, gpb, 4, 768, 768);

  // fused LN/ELU/projection/sigmoid/mask
  fused_kernel<<<65536 / 32, 256, 0, stream>>>(aM, b2M, gpb, gamma, beta, WoT, bo, mask, out);
}

// Round 2
// 133.649 us; speedup vs baseline: 4.6212x; 4.6212x over previous
//
#include <hip/hip_runtime.h>
#include <hip/hip_bf16.h>
#include <stdint.h>

#define L_ 128
#define B_ 4
#define H_ 768
#define R_ 97
#define LN_EPS 1e-5f

typedef _Float16 f16x8 __attribute__((ext_vector_type(8)));
typedef _Float16 f16x2 __attribute__((ext_vector_type(2)));
typedef float f32x4 __attribute__((ext_vector_type(4)));

// ---------------- prep: concat [h1|h2] -> f16 ccH[512][1536] ----------------
__global__ __launch_bounds__(256) void prep_cc(const float* __restrict__ h1,
                                               const float* __restrict__ h2,
                                               _Float16* __restrict__ ccH) {
  int lb = blockIdx.x;
  const float2* s1 = (const float2*)(h1 + (size_t)lb * H_);
  const float2* s2 = (const float2*)(h2 + (size_t)lb * H_);
  f16x2* d = (f16x2*)(ccH + (size_t)lb * (2 * H_));
  for (int i = threadIdx.x; i < H_ / 2; i += 256) {
    float2 v = s1[i]; f16x2 o; o[0] = (_Float16)v.x; o[1] = (_Float16)v.y; d[i] = o;
  }
  for (int i = threadIdx.x; i < H_ / 2; i += 256) {
    float2 v = s2[i]; f16x2 o; o[0] = (_Float16)v.x; o[1] = (_Float16)v.y; d[H_ / 2 + i] = o;
  }
}

// ---------------- pack big B: [Wr^T | W1^T(zero-pad k<768) | W2^T(zero-pad)] ----------------
// fragment layout: half index f = ((kstep*144 + ntile)*64 + kg*16 + nm)*8 + j
// where k = kstep*32 + kg*8 + j, n = ntile*16 + nm.
__global__ __launch_bounds__(256) void pack_big(const float* __restrict__ Wr,
                                                const float* __restrict__ Wh,
                                                _Float16* __restrict__ Bp) {
  int t = blockIdx.x * 256 + threadIdx.x;        // 1,769,472 threads; 2 halves each
  int f = t * 2;
  int j = f & 7;
  int u = f >> 3;
  int nm = u & 15; u >>= 4;
  int kg = u & 3;  u >>= 2;
  int nt = u % 144;
  int ks = u / 144;
  int k = ks * 32 + kg * 8 + j;
  int n = nt * 16 + nm;
  float v0, v1;
  if (n < 768) {
    v0 = Wr[(size_t)n * 1536 + k];
    v1 = Wr[(size_t)n * 1536 + k + 1];
  } else if (n < 1536) {
    int n2 = n - 768;
    if (k >= 768) { v0 = Wh[(size_t)n2 * 2304 + (k - 768)]; v1 = Wh[(size_t)n2 * 2304 + (k - 767)]; }
    else { v0 = 0.f; v1 = 0.f; }
  } else {
    int n2 = n - 1536;
    if (k >= 768) { v0 = Wh[(size_t)n2 * 2304 + 768 + (k - 768)]; v1 = Wh[(size_t)n2 * 2304 + 768 + (k - 767)]; }
    else { v0 = 0.f; v1 = 0.f; }
  }
  f16x2 o; o[0] = (_Float16)v0; o[1] = (_Float16)v1;
  *(f16x2*)(Bp + f) = o;
}

// ---------------- pack Wo -> fragments, N padded 97->128 ----------------
__global__ __launch_bounds__(256) void pack_wo(const float* __restrict__ Wo,
                                               _Float16* __restrict__ WoP) {
  int t = blockIdx.x * 256 + threadIdx.x;        // 49,152 threads; 2 halves each
  int f = t * 2;
  int j = f & 7;
  int u = f >> 3;
  int nm = u & 15; u >>= 4;
  int kg = u & 3;  u >>= 2;
  int nt = u & 7;
  int ks = u >> 3;
  int k = ks * 32 + kg * 8 + j;
  int n = nt * 16 + nm;
  float v0 = 0.f, v1 = 0.f;
  if (n < R_) { v0 = Wo[(size_t)n * H_ + k]; v1 = Wo[(size_t)n * H_ + k + 1]; }
  f16x2 o; o[0] = (_Float16)v0; o[1] = (_Float16)v1;
  *(f16x2*)(WoP + f) = o;
}

// ---------------- big MFMA GEMM: C[512][2304] = ccH * Bp ----------------
// block tile 32x128 (grid 18 x 16); wave: mtile=w&1, 4 ntiles at (w>>1)*4.
// epilogue: cols <768 -> g=tanh(+br) f32; <1536 -> aH f16; else bH f16.
__global__ __launch_bounds__(256) void gemm_big(const _Float16* __restrict__ A,   // [512][1536]
                                                const _Float16* __restrict__ Bp,
                                                const float* __restrict__ br,
                                                float* __restrict__ g,
                                                _Float16* __restrict__ aH,
                                                _Float16* __restrict__ bH) {
  int w = threadIdx.x >> 6, l = threadIdx.x & 63;
  int bn = blockIdx.x, bm = blockIdx.y;
  int row0 = bm * 32 + (w & 1) * 16;
  int ntb = bn * 8 + (w >> 1) * 4;
  const _Float16* ap = A + (size_t)(row0 + (l & 15)) * 1536 + (l >> 4) * 8;
  const _Float16* bp = Bp + (size_t)ntb * 512 + l * 8;
  f32x4 acc[4] = {};
  for (int ks = 0; ks < 48; ++ks) {
    f16x8 av = *(const f16x8*)(ap + ks * 32);
    const _Float16* bk = bp + (size_t)ks * (144 * 512);
#pragma unroll
    for (int q = 0; q < 4; ++q) {
      f16x8 bv = *(const f16x8*)(bk + q * 512);
      acc[q] = __builtin_amdgcn_mfma_f32_16x16x32_f16(av, bv, acc[q], 0, 0, 0);
    }
  }
  int colb = bn * 128 + (w >> 1) * 64;
#pragma unroll
  for (int q = 0; q < 4; ++q) {
    int col = colb + q * 16 + (l & 15);
#pragma unroll
    for (int r = 0; r < 4; ++r) {
      int row = row0 + (l >> 4) * 4 + r;
      float v = acc[q][r];
      if (col < 768) {
        g[(size_t)row * H_ + col] = tanhf(v + br[col]);
      } else if (col < 1536) {
        aH[(size_t)row * H_ + (col - 768)] = (_Float16)v;
      } else {
        bH[(size_t)row * H_ + (col - 1536)] = (_Float16)v;
      }
    }
  }
}

// ---------------- max over l: gmax[b][h] = max_l g[(l*B+b)][h] ----------------
__global__ __launch_bounds__(256) void maxred_kernel(const float* __restrict__ g,
                                                     float* __restrict__ gmax) {
  int t = blockIdx.x * 256 + threadIdx.x;
  if (t >= B_ * H_) return;
  int b = t / H_, h = t - b * H_;
  float m = -3.4e38f;
  for (int l = 0; l < L_; ++l) m = fmaxf(m, g[((size_t)(l * B_ + b)) * H_ + h]);
  gmax[t] = m;
}

// ---------------- gp[b][n] = sum_i gmax[b][i]*Wh[n][1536+i] + bh[n] ----------------
// one wave per b (4 waves/block), one block per n.
__global__ __launch_bounds__(256) void gp_kernel(const float* __restrict__ Wh,
                                                 const float* __restrict__ gmax,
                                                 const float* __restrict__ bh,
                                                 float* __restrict__ gpv) {
  int n = blockIdx.x;
  int w = threadIdx.x >> 6, l = threadIdx.x & 63;
  const float* wr = Wh + (size_t)n * 2304 + 1536;
  const float* gm = gmax + (size_t)w * H_;
  float s = 0.f;
#pragma unroll
  for (int t = 0; t < 12; ++t) {
    int i = l + 64 * t;
    s += wr[i] * gm[i];
  }
#pragma unroll
  for (int off = 32; off; off >>= 1) s += __shfl_xor(s, off);
  if (l == 0) gpv[(size_t)w * H_ + n] = s + bh[n];
}

// ---------------- fused: pre -> LN -> ELU -> MFMA proj -> sigmoid*mask ----------------
// 32 rows/block, 4 waves; Xs padded to 776 halves/row (2-way banks on frag reads).
#define XPAD 776
__global__ __launch_bounds__(256) void fused(const _Float16* __restrict__ aH,
                                             const _Float16* __restrict__ bH,
                                             const float* __restrict__ gp,
                                             const float* __restrict__ gamma,
                                             const float* __restrict__ beta,
                                             const _Float16* __restrict__ WoP,
                                             const float* __restrict__ bo,
                                             const float* __restrict__ mask,
                                             float* __restrict__ out) {
  __shared__ _Float16 Xs[32 * XPAD];
  int tid = threadIdx.x, l = tid & 63, w = tid >> 6;
  int m0 = blockIdx.x * 32;
  int kk = m0 >> 9;

  // phase 1: LN + ELU -> f16 LDS rows (wave w owns rows 8w..8w+7)
  for (int j = 0; j < 8; ++j) {
    int rr = w * 8 + j;
    int row = m0 + rr;
    int b = row & 3, li = (row >> 2) & 127;
    const f16x2* ap = (const f16x2*)(aH + (size_t)(kk * B_ + b) * H_);
    const f16x2* bp = (const f16x2*)(bH + (size_t)(li * B_ + b) * H_);
    const float2* gpr = (const float2*)(gp + (size_t)b * H_);
    float v0[6], v1[6];
    float s = 0.f, sq = 0.f;
#pragma unroll
    for (int t = 0; t < 6; ++t) {
      int p = l + 64 * t;
      f16x2 a2 = ap[p];
      f16x2 b2 = bp[p];
      float2 g2 = gpr[p];
      float x0 = (float)a2[0] + (float)b2[0] + g2.x;
      float x1 = (float)a2[1] + (float)b2[1] + g2.y;
      v0[t] = x0; v1[t] = x1;
      s += x0 + x1;
      sq += x0 * x0 + x1 * x1;
    }
#pragma unroll
    for (int off = 32; off; off >>= 1) {
      s += __shfl_xor(s, off);
      sq += __shfl_xor(sq, off);
    }
    float mu = s * (1.f / H_);
    float var = sq * (1.f / H_) - mu * mu;
    float rs = rsqrtf(var + LN_EPS);
#pragma unroll
    for (int t = 0; t < 6; ++t) {
      int h = 2 * l + 128 * t;
      float2 gm = *(const float2*)(gamma + h);
      float2 bt = *(const float2*)(beta + h);
      float y0 = (v0[t] - mu) * rs * gm.x + bt.x;
      float y1 = (v1[t] - mu) * rs * gm.y + bt.y;
      y0 = y0 > 0.f ? y0 : (__expf(y0) - 1.f);
      y1 = y1 > 0.f ? y1 : (__expf(y1) - 1.f);
      f16x2 o; o[0] = (_Float16)y0; o[1] = (_Float16)y1;
      *(f16x2*)(Xs + (size_t)rr * XPAD + h) = o;
    }
  }
  __syncthreads();

  // phase 2: MFMA projection. wave: mtile=w&1, ntiles (w>>1)*4..+3
  int mt = w & 1, nq = w >> 1;
  const _Float16* xbase = Xs + (size_t)(mt * 16 + (l & 15)) * XPAD + (l >> 4) * 8;
  const _Float16* wbase = WoP + (size_t)(nq * 4) * 512 + l * 8;
  f32x4 acc[4] = {};
  for (int ks = 0; ks < 24; ++ks) {
    f16x8 av = *(const f16x8*)(xbase + ks * 32);
    const _Float16* bk = wbase + (size_t)ks * (8 * 512);
#pragma unroll
    for (int q = 0; q < 4; ++q) {
      f16x8 bv = *(const f16x8*)(bk + q * 512);
      acc[q] = __builtin_amdgcn_mfma_f32_16x16x32_f16(av, bv, acc[q], 0, 0, 0);
    }
  }
  // epilogue: bias, sigmoid, mask
#pragma unroll
  for (int q = 0; q < 4; ++q) {
    int col = nq * 64 + q * 16 + (l & 15);
    if (col < R_) {
      float bov = bo[col];
#pragma unroll
      for (int r = 0; r < 4; ++r) {
        int row = m0 + mt * 16 + (l >> 4) * 4 + r;
        int b = row & 3, li = (row >> 2) & 127;
        float mv = mask[kk * B_ + b] * mask[li * B_ + b];
        float z = acc[q][r] + bov;
        out[(size_t)row * R_ + col] = mv / (1.f + __expf(-z));
      }
    }
  }
}

extern "C" void kernel_launch(void* const* d_in, const int* in_sizes, int n_in,
                              void* d_out, int out_size, void* d_ws, size_t ws_size,
                              hipStream_t stream) {
  const float* h1    = (const float*)d_in[0];
  const float* h2    = (const float*)d_in[1];
  const float* mask  = (const float*)d_in[2];
  const float* Wr    = (const float*)d_in[3];
  const float* br    = (const float*)d_in[4];
  const float* Wh    = (const float*)d_in[5];
  const float* bh    = (const float*)d_in[6];
  const float* gamma = (const float*)d_in[7];
  const float* beta  = (const float*)d_in[8];
  const float* Wo    = (const float*)d_in[9];
  const float* bo    = (const float*)d_in[10];
  float* out = (float*)d_out;
  float* ws = (float*)d_ws;

  // ws layout (float units)
  _Float16* ccH = (_Float16*)ws;                        // 786,432 halves  (393,216 f)
  _Float16* Bp  = (_Float16*)(ws + 393216);             // 3,538,944 halves (1,769,472 f)
  _Float16* WoP = (_Float16*)(ws + 393216 + 1769472);   // 98,304 halves   (49,152 f)
  float* g    = ws + 2211840;                           // 393,216 f
  float* gmax = g + 393216;                             // 3,072 f
  float* gpv  = gmax + 3072;                            // 3,072 f
  _Float16* aH = (_Float16*)(gpv + 3072);               // 393,216 halves (196,608 f)
  _Float16* bH = (_Float16*)((float*)(gpv + 3072) + 196608);

  prep_cc<<<512, 256, 0, stream>>>(h1, h2, ccH);
  pack_big<<<6912, 256, 0, stream>>>(Wr, Wh, Bp);
  pack_wo<<<192, 256, 0, stream>>>(Wo, WoP);

  gemm_big<<<dim3(18, 16), 256, 0, stream>>>(ccH, Bp, br, g, aH, bH);
  maxred_kernel<<<12, 256, 0, stream>>>(g, gmax);
  gp_kernel<<<768, 256, 0, stream>>>(Wh, gmax, bh, gpv);

  fused<<<65536 / 32, 256, 0, stream>>>(aH, bH, gpv, gamma, beta, WoP, bo, mask, out);
}

// Round 5
// 103.270 us; speedup vs baseline: 5.9806x; 1.2942x over previous
//
#include <hip/hip_runtime.h>
#include <hip/hip_bf16.h>
#include <stdint.h>

#define L_ 128
#define B_ 4
#define H_ 768
#define R_ 97
#define LN_EPS 1e-5f

typedef _Float16 f16x8 __attribute__((ext_vector_type(8)));
typedef _Float16 f16x4 __attribute__((ext_vector_type(4)));
typedef _Float16 f16x2 __attribute__((ext_vector_type(2)));
typedef float f32x4 __attribute__((ext_vector_type(4)));

// ================= merged prep: cc-concat, Bp pack, WoP pack, gamma/beta f16 ==========
// fragment layout for B operands: half index f = ((ks*NT + nt)*64 + l)*8 + j
// where lane l holds col n = nt*16 + (l&15), k = ks*32 + (l>>4)*8 + j.
__global__ __launch_bounds__(256) void prep_all(const float* __restrict__ h1,
                                                const float* __restrict__ h2,
                                                const float* __restrict__ Wr,
                                                const float* __restrict__ Wh,
                                                const float* __restrict__ Wo,
                                                const float* __restrict__ gamma,
                                                const float* __restrict__ beta,
                                                _Float16* __restrict__ ccH,
                                                _Float16* __restrict__ Bp,
                                                _Float16* __restrict__ WoP,
                                                _Float16* __restrict__ gbH) {
  int blk = blockIdx.x;
  if (blk < 512) {                          // ---- concat h1|h2 -> f16 [512][1536]
    const float2* s1 = (const float2*)(h1 + (size_t)blk * H_);
    const float2* s2 = (const float2*)(h2 + (size_t)blk * H_);
    f16x2* d = (f16x2*)(ccH + (size_t)blk * (2 * H_));
    for (int i = threadIdx.x; i < H_ / 2; i += 256) {
      float2 v = s1[i]; f16x2 o; o[0] = (_Float16)v.x; o[1] = (_Float16)v.y; d[i] = o;
    }
    for (int i = threadIdx.x; i < H_ / 2; i += 256) {
      float2 v = s2[i]; f16x2 o; o[0] = (_Float16)v.x; o[1] = (_Float16)v.y; d[H_ / 2 + i] = o;
    }
    return;
  }
  blk -= 512;
  if (blk < 6912) {                         // ---- pack [Wr^T | W1^T(pad) | W2^T(pad)], NT=144
    int f = (blk * 256 + threadIdx.x) * 2;
    int j = f & 7;
    int u = f >> 3;
    int lidx = u & 63; u >>= 6;
    int nt = u % 144;
    int ks = u / 144;
    int k = ks * 32 + (lidx >> 4) * 8 + j;
    int n = nt * 16 + (lidx & 15);
    float v0, v1;
    if (n < 768) {
      v0 = Wr[(size_t)n * 1536 + k];
      v1 = Wr[(size_t)n * 1536 + k + 1];
    } else if (n < 1536) {
      int n2 = n - 768;
      if (k >= 768) { v0 = Wh[(size_t)n2 * 2304 + (k - 768)]; v1 = Wh[(size_t)n2 * 2304 + (k - 767)]; }
      else { v0 = 0.f; v1 = 0.f; }
    } else {
      int n2 = n - 1536;
      if (k >= 768) { v0 = Wh[(size_t)n2 * 2304 + 768 + (k - 768)]; v1 = Wh[(size_t)n2 * 2304 + 768 + (k - 767)]; }
      else { v0 = 0.f; v1 = 0.f; }
    }
    f16x2 o; o[0] = (_Float16)v0; o[1] = (_Float16)v1;
    *(f16x2*)(Bp + f) = o;
    return;
  }
  blk -= 6912;
  if (blk < 192) {                          // ---- pack Wo [97x768] -> frags, N pad 128, NT=8
    int f = (blk * 256 + threadIdx.x) * 2;
    int j = f & 7;
    int u = f >> 3;
    int lidx = u & 63; u >>= 6;
    int nt = u & 7;
    int ks = u >> 3;
    int k = ks * 32 + (lidx >> 4) * 8 + j;
    int n = nt * 16 + (lidx & 15);
    float v0 = 0.f, v1 = 0.f;
    if (n < R_) { v0 = Wo[(size_t)n * H_ + k]; v1 = Wo[(size_t)n * H_ + k + 1]; }
    f16x2 o; o[0] = (_Float16)v0; o[1] = (_Float16)v1;
    *(f16x2*)(WoP + f) = o;
    return;
  }
  blk -= 192;                               // ---- gamma/beta -> f16 (3 blocks)
  int i = blk * 256 + threadIdx.x;
  if (i < H_) {
    gbH[i] = (_Float16)gamma[i];
    gbH[H_ + i] = (_Float16)beta[i];
  }
}

// ================= big MFMA GEMM: [512][2304] = ccH * Bp; tile 32x64, 576 blocks =======
// epilogue: col<768 -> tanh(+br)+1 atomicMax (uint trick); else aH / bH f16.
__global__ __launch_bounds__(256) void gemm_big(const _Float16* __restrict__ A,
                                                const _Float16* __restrict__ Bp,
                                                const float* __restrict__ br,
                                                unsigned int* __restrict__ gmaxU,
                                                _Float16* __restrict__ aH,
                                                _Float16* __restrict__ bH) {
  int w = threadIdx.x >> 6, l = threadIdx.x & 63;
  int nb = blockIdx.x, mb = blockIdx.y;
  int row0 = mb * 32 + (w & 1) * 16;
  int nt0 = nb * 4 + (w >> 1) * 2;
  const f16x8* ap = (const f16x8*)(A + (size_t)(row0 + (l & 15)) * 1536 + (l >> 4) * 8);
  const f16x8* bp = (const f16x8*)(Bp + ((size_t)nt0 * 64 + l) * 8);
  // strides in f16x8 units: A per-ks = 4; B per-ks = 144*64 = 9216; B per-nt = 64.
  f32x4 acc0 = {}, acc1 = {};
  f16x8 ac = ap[0], b0c = bp[0], b1c = bp[64];
  for (int ks = 0; ks < 48; ++ks) {
    f16x8 an = {}, b0n = {}, b1n = {};
    if (ks < 47) {
      an = ap[(ks + 1) * 4];
      b0n = bp[(size_t)(ks + 1) * 9216];
      b1n = bp[(size_t)(ks + 1) * 9216 + 64];
    }
    acc0 = __builtin_amdgcn_mfma_f32_16x16x32_f16(ac, b0c, acc0, 0, 0, 0);
    acc1 = __builtin_amdgcn_mfma_f32_16x16x32_f16(ac, b1c, acc1, 0, 0, 0);
    ac = an; b0c = b0n; b1c = b1n;
  }
#pragma unroll
  for (int q = 0; q < 2; ++q) {
    f32x4 acc = q ? acc1 : acc0;
    int col = nb * 64 + (w >> 1) * 32 + q * 16 + (l & 15);
#pragma unroll
    for (int r = 0; r < 4; ++r) {
      int row = row0 + (l >> 4) * 4 + r;
      float v = acc[r];
      if (col < 768) {
        float t = tanhf(v + br[col]) + 1.0f;   // >0 => uint-monotone
        atomicMax(&gmaxU[(row & 3) * H_ + col], __float_as_uint(t));
      } else if (col < 1536) {
        aH[(size_t)row * H_ + (col - 768)] = (_Float16)v;
      } else {
        bH[(size_t)row * H_ + (col - 1536)] = (_Float16)v;
      }
    }
  }
}

// ================= gp[b][n] = dot(gmax[b,:], Wh[n,1536:2304]) + bh[n] =================
__global__ __launch_bounds__(256) void gp_kernel(const float* __restrict__ Wh,
                                                 const unsigned int* __restrict__ gmaxU,
                                                 const float* __restrict__ bh,
                                                 float* __restrict__ gpv) {
  int n = blockIdx.x;
  int w = threadIdx.x >> 6, l = threadIdx.x & 63;
  const float* wr = Wh + (size_t)n * 2304 + 1536;
  const unsigned int* gm = gmaxU + (size_t)w * H_;
  float s = 0.f;
#pragma unroll
  for (int t = 0; t < 12; ++t) {
    int i = l + 64 * t;
    s += wr[i] * (__uint_as_float(gm[i]) - 1.0f);
  }
#pragma unroll
  for (int off = 32; off; off >>= 1) s += __shfl_xor(s, off);
  if (l == 0) gpv[(size_t)w * H_ + n] = s + bh[n];
}

// ================= stats: aH2 = f16(aH + gp); S,Q per row for aH2 (0..511) and bH (512..1023)
__global__ __launch_bounds__(256) void stats(const _Float16* __restrict__ aH,
                                             const _Float16* __restrict__ bH,
                                             const float* __restrict__ gpv,
                                             _Float16* __restrict__ aH2,
                                             float* __restrict__ S,
                                             float* __restrict__ Q) {
  int r = blockIdx.x * 4 + (threadIdx.x >> 6);
  int l = threadIdx.x & 63;
  float s = 0.f, q = 0.f;
  if (r < 512) {
    int b = r & 3;
    const f16x4* ap = (const f16x4*)(aH + (size_t)r * H_);
    const float4* gp4 = (const float4*)(gpv + (size_t)b * H_);
    f16x4* op = (f16x4*)(aH2 + (size_t)r * H_);
#pragma unroll
    for (int t = 0; t < 3; ++t) {
      int i = t * 64 + l;
      f16x4 av = ap[i];
      float4 g4 = gp4[i];
      f16x4 o;
      o[0] = (_Float16)((float)av[0] + g4.x);
      o[1] = (_Float16)((float)av[1] + g4.y);
      o[2] = (_Float16)((float)av[2] + g4.z);
      o[3] = (_Float16)((float)av[3] + g4.w);
      op[i] = o;
#pragma unroll
      for (int j = 0; j < 4; ++j) { float y = (float)o[j]; s += y; q += y * y; }
    }
  } else {
    const f16x4* bp = (const f16x4*)(bH + (size_t)(r - 512) * H_);
#pragma unroll
    for (int t = 0; t < 3; ++t) {
      f16x4 bv = bp[t * 64 + l];
#pragma unroll
      for (int j = 0; j < 4; ++j) { float y = (float)bv[j]; s += y; q += y * y; }
    }
  }
#pragma unroll
  for (int off = 32; off; off >>= 1) {
    s += __shfl_xor(s, off);
    q += __shfl_xor(q, off);
  }
  if (l == 0) { S[r] = s; Q[r] = q; }
}

// ================= dotab: cross dot -> mu/rs per (k,l,b) row via MFMA ===================
// grid (2 ltq, 8 kt, 4 b), 4 waves: wave w -> l-tile lt = ltq*4+w (16 cols), 16 k-rows.
// K = H_ = 768 -> 24 k-steps of 32 (NOT 48 — that was the round-3/4 bug: the dot
// overran into the next row, perturbing var by ~2%, absmax 7e-2).
__global__ __launch_bounds__(256) void dotab(const _Float16* __restrict__ aH2,
                                             const _Float16* __restrict__ bH,
                                             const float* __restrict__ S,
                                             const float* __restrict__ Q,
                                             float* __restrict__ mu_arr,
                                             float* __restrict__ rs_arr) {
  int w = threadIdx.x >> 6, l = threadIdx.x & 63;
  int ltq = blockIdx.x, kt = blockIdx.y, b = blockIdx.z;
  int lt = ltq * 4 + w;
  const f16x8* ap = (const f16x8*)(aH2 + ((size_t)(kt * 16 + (l & 15)) * 4 + b) * H_ + (l >> 4) * 8);
  const f16x8* bp = (const f16x8*)(bH + ((size_t)(lt * 16 + (l & 15)) * 4 + b) * H_ + (l >> 4) * 8);
  f32x4 acc = {};
  f16x8 a0 = ap[0], b0 = bp[0], a1 = ap[4], b1 = bp[4];
  for (int ks = 0; ks < 24; ++ks) {
    f16x8 a2 = {}, b2 = {};
    if (ks < 22) { a2 = ap[(ks + 2) * 4]; b2 = bp[(ks + 2) * 4]; }
    acc = __builtin_amdgcn_mfma_f32_16x16x32_f16(a0, b0, acc, 0, 0, 0);
    a0 = a1; b0 = b1; a1 = a2; b1 = b2;
  }
#pragma unroll
  for (int r = 0; r < 4; ++r) {
    int k = kt * 16 + (l >> 4) * 4 + r;
    int lg = lt * 16 + (l & 15);
    int arow = k * 4 + b, brow = lg * 4 + b;
    float mu = (S[arow] + S[512 + brow]) * (1.f / H_);
    float q2 = Q[arow] + Q[512 + brow] + 2.f * acc[r];
    float var = fmaxf(q2 * (1.f / H_) - mu * mu, 0.f);   // guard: true var >= 0
    float rs = rsqrtf(var + LN_EPS);
    size_t idx = (size_t)k * 512 + (size_t)lg * 4 + b;
    mu_arr[idx] = mu;
    rs_arr[idx] = rs;
  }
}

// ================= fused: build ELU(LN(pre)) frags in-reg, MFMA vs LDS-staged Wo ========
// M=64 rows/block (wave w owns 16 rows), 8 ntiles (128 cols, R=97 live). 1024 blocks.
// Double-buffered Wo staging with plain __syncthreads (compiler+HW fence, race-free).
__global__ __launch_bounds__(256) void fused2(const _Float16* __restrict__ aH2,
                                              const _Float16* __restrict__ bH,
                                              const _Float16* __restrict__ gbH,
                                              const _Float16* __restrict__ WoP,
                                              const float* __restrict__ bo,
                                              const float* __restrict__ mask,
                                              const float* __restrict__ mu_arr,
                                              const float* __restrict__ rs_arr,
                                              float* __restrict__ out) {
  __shared__ __align__(16) _Float16 WoLds[2][4096];   // 2 x 8KB (one ks-chunk)
  int tid = threadIdx.x, w = tid >> 6, l = tid & 63;
  int m0 = blockIdx.x * 64;
  int myrow = m0 + w * 16 + (l & 15);
  int b = myrow & 3, li = (myrow >> 2) & 127, kk = myrow >> 9;
  const f16x8* ap = (const f16x8*)(aH2 + ((size_t)kk * 4 + b) * H_ + (l >> 4) * 8);
  const f16x8* bp = (const f16x8*)(bH + ((size_t)li * 4 + b) * H_ + (l >> 4) * 8);
  const f16x8* gp8 = (const f16x8*)(gbH + (l >> 4) * 8);
  const f16x8* be8 = (const f16x8*)(gbH + H_ + (l >> 4) * 8);
  float mu = mu_arr[myrow], rs = rs_arr[myrow];

  const uint4* wog = (const uint4*)WoP;               // 512 uint4 per ks-chunk
  uint4* lds0 = (uint4*)&WoLds[0][0];
  lds0[tid] = wog[tid];
  lds0[256 + tid] = wog[256 + tid];
  __syncthreads();

  f32x4 acc[8] = {};
  for (int ks = 0; ks < 24; ++ks) {
    int cur = ks & 1;
    uint4 wo0 = {}, wo1 = {};
    if (ks < 23) {                                     // prefetch next chunk to regs
      wo0 = wog[(ks + 1) * 512 + tid];
      wo1 = wog[(ks + 1) * 512 + 256 + tid];
    }
    // ---- build A-fragment: x = a+b; y = (x-mu)*rs*gamma + beta; elu ----
    f16x8 a8 = ap[ks * 4];
    f16x8 b8 = bp[ks * 4];
    f16x8 g8 = gp8[ks * 4];
    f16x8 e8 = be8[ks * 4];
    f16x8 av;
#pragma unroll
    for (int j = 0; j < 8; ++j) {
      float x = (float)a8[j] + (float)b8[j];
      float t = rs * (float)g8[j];
      float y = (x - mu) * t + (float)e8[j];
      float e = __expf(y) - 1.f;
      y = y > 0.f ? y : e;
      av[j] = (_Float16)y;
    }
    __syncthreads();                     // all waves done READING buf cur^1 (prev iter)
    if (ks < 23) {
      uint4* d = (uint4*)&WoLds[cur ^ 1][0];
      d[tid] = wo0;
      d[256 + tid] = wo1;
    }
    __syncthreads();                     // writes to buf cur^1 visible before next reads
    const f16x8* bvp = (const f16x8*)&WoLds[cur][0];
#pragma unroll
    for (int q = 0; q < 8; ++q) {
      f16x8 bv = bvp[q * 64 + l];
      acc[q] = __builtin_amdgcn_mfma_f32_16x16x32_f16(av, bv, acc[q], 0, 0, 0);
    }
  }
  // ---- epilogue: bias, sigmoid, mask ----
  float mv[4];
#pragma unroll
  for (int r = 0; r < 4; ++r) {
    int row = m0 + w * 16 + (l >> 4) * 4 + r;
    int bb = row & 3, ll = (row >> 2) & 127, kx = row >> 9;
    mv[r] = mask[kx * 4 + bb] * mask[ll * 4 + bb];
  }
#pragma unroll
  for (int q = 0; q < 8; ++q) {
    int col = q * 16 + (l & 15);
    if (col < R_) {
      float bov = bo[col];
#pragma unroll
      for (int r = 0; r < 4; ++r) {
        int row = m0 + w * 16 + (l >> 4) * 4 + r;
        float z = acc[q][r] + bov;
        out[(size_t)row * R_ + col] = mv[r] / (1.f + __expf(-z));
      }
    }
  }
}

extern "C" void kernel_launch(void* const* d_in, const int* in_sizes, int n_in,
                              void* d_out, int out_size, void* d_ws, size_t ws_size,
                              hipStream_t stream) {
  const float* h1    = (const float*)d_in[0];
  const float* h2    = (const float*)d_in[1];
  const float* mask  = (const float*)d_in[2];
  const float* Wr    = (const float*)d_in[3];
  const float* br    = (const float*)d_in[4];
  const float* Wh    = (const float*)d_in[5];
  const float* bh    = (const float*)d_in[6];
  const float* gamma = (const float*)d_in[7];
  const float* beta  = (const float*)d_in[8];
  const float* Wo    = (const float*)d_in[9];
  const float* bo    = (const float*)d_in[10];
  float* out = (float*)d_out;
  char* ws = (char*)d_ws;

  // ws layout (bytes, 16B-aligned chunks)
  _Float16* ccH = (_Float16*)ws;                    size_t off = 512 * 1536 * 2;       // 1.5MB
  _Float16* Bp  = (_Float16*)(ws + off);            off += (size_t)1536 * 2304 * 2;    // 7MB
  _Float16* WoP = (_Float16*)(ws + off);            off += 768 * 128 * 2;              // 192KB
  _Float16* gbH = (_Float16*)(ws + off);            off += 4096;
  _Float16* aH  = (_Float16*)(ws + off);            off += 512 * 768 * 2;
  _Float16* bH  = (_Float16*)(ws + off);            off += 512 * 768 * 2;
  _Float16* aH2 = (_Float16*)(ws + off);            off += 512 * 768 * 2;
  unsigned int* gmaxU = (unsigned int*)(ws + off);  off += 3072 * 4;
  float* gpv = (float*)(ws + off);                  off += 3072 * 4;
  float* S   = (float*)(ws + off);                  off += 1024 * 4;
  float* Q   = (float*)(ws + off);                  off += 1024 * 4;
  float* mu_arr = (float*)(ws + off);               off += 65536 * 4;
  float* rs_arr = (float*)(ws + off);               off += 65536 * 4;

  prep_all<<<512 + 6912 + 192 + 3, 256, 0, stream>>>(h1, h2, Wr, Wh, Wo, gamma, beta,
                                                     ccH, Bp, WoP, gbH);
  hipMemsetAsync(gmaxU, 0, 3072 * 4, stream);

  gemm_big<<<dim3(36, 16), 256, 0, stream>>>(ccH, Bp, br, gmaxU, aH, bH);
  gp_kernel<<<768, 256, 0, stream>>>(Wh, gmaxU, bh, gpv);
  stats<<<256, 256, 0, stream>>>(aH, bH, gpv, aH2, S, Q);
  dotab<<<dim3(2, 8, 4), 256, 0, stream>>>(aH2, bH, S, Q, mu_arr, rs_arr);

  fused2<<<1024, 256, 0, stream>>>(aH2, bH, gbH, WoP, bo, mask, mu_arr, rs_arr, out);
}